// Round 15
// baseline (1602.703 us; speedup 1.0000x reference)
//
#include <hip/hip_runtime.h>
#include <stdint.h>

typedef __attribute__((ext_vector_type(8))) short short8;
typedef __attribute__((ext_vector_type(4))) float floatx4;

#define P_TOT (16 * 256 * 256)
#define P_IMG 65536
#define TPS 3208   // tile plane stride (shorts) per channel-octet: 400*8 + 8

__device__ __forceinline__ unsigned short f2bf(float f) {
    unsigned int u = __float_as_uint(f);
    return (unsigned short)((u + 0x7FFFu + ((u >> 16) & 1u)) >> 16);
}
__device__ __forceinline__ float bf2f(unsigned short h) {
    return __uint_as_float(((unsigned int)h) << 16);
}

// ---- single-launch repack: all 6 OIHW fp32 packs -> bf16 MFMA B-order -------
__global__ void repack_all(const float* __restrict__ w2x, const float* __restrict__ w3x,
                           const float* __restrict__ w2g, const float* __restrict__ w3g,
                           const float* __restrict__ c2w, const float* __restrict__ c3w,
                           unsigned short* __restrict__ bp) {
    int idx = blockIdx.x * 256 + threadIdx.x;
    if (idx >= 230400) return;
    const float* w; int creal, loc;
    if      (idx < 36864)  { w = w2x; creal = 64; loc = idx; }
    else if (idx < 92160)  { w = w3x; creal = 81; loc = idx - 36864; }
    else if (idx < 129024) { w = w2g; creal = 64; loc = idx - 92160; }
    else if (idx < 184320) { w = w3g; creal = 81; loc = idx - 129024; }
    else if (idx < 221184) { w = c2w; creal = 64; loc = idx - 184320; }
    else                   { w = c3w; creal = 1;  loc = idx - 221184; }
    int j = loc & 7;
    int lane = (loc >> 3) & 63;
    int gt = loc >> 9;            // g*18 + t
    int t = gt % 18;
    int n = (gt / 18) * 16 + (lane & 15);
    int tap = t >> 1, hf = t & 1;
    int dy = tap / 3, dx = tap % 3;
    int cin = hf * 32 + (lane >> 4) * 8 + j;
    float v = (n < creal) ? w[((n * 64 + cin) * 3 + dy) * 3 + dx] : 0.f;
    bp[idx] = f2bf(v);
}

// ---- fused conv3x3 (NCIN->64, relu) + conv3x3 (64->NG*16, relu) via MFMA ----
// VALU-slim h1: fp32 weights in LDS (no per-use converts), incremental rr/cc
// (no divides), hoisted bias. (512,4) -> VGPR<=64, 2 blocks/CU (r14-proven).
template <int NG, int NCIN>
__global__ __launch_bounds__(512, 4) void conv_fused12(
    const float* __restrict__ xin, const float* __restrict__ w1,
    const float* __restrict__ b1, const unsigned short* __restrict__ bp,
    const float* __restrict__ bias2, unsigned short* __restrict__ hout) {
    constexpr int GH = NG / 2;
    __shared__ __align__(16) unsigned short tile[8 * TPS];      // [cg][pix<=400][8ch]
    __shared__ __align__(16) float xt2[8 * 72 * NCIN];
    __shared__ __align__(16) float wtf[9 * 64 * NCIN];          // fp32
    __shared__ float bt[64];
    int blk = blockIdx.x;
    int n = blk >> 8;
    int rem = blk & 255;
    int h0 = (rem >> 2) * 4;
    int w0 = (rem & 3) * 64;
    int tid = threadIdx.x;
    // stage conv1 weights [tap*NCIN+ci][ch] (fp32) and bias
    for (int i = tid; i < 576 * NCIN; i += 512) {
        int ch = i & 63, tc = i >> 6;          // tc = tap*NCIN + ci
        int tap = tc / NCIN, ci = tc % NCIN;
        wtf[tc * 64 + ch] = w1[(ch * NCIN + ci) * 9 + tap];
    }
    if (tid < 64) bt[tid] = b1[tid];
    // stage x tile: rows h0-2..h0+5, cols w0-2..w0+65 (zero-padded)
    const float* xb = xin + (((size_t)n) << 16) * NCIN;
    for (int i = tid; i < 8 * 68; i += 512) {
        int cc = i % 68, rr = i / 68;
        int gh = h0 - 2 + rr, gw = w0 - 2 + cc;
        bool ok = (gh >= 0 && gh < 256 && gw >= 0 && gw < 256);
        if (NCIN == 1) {
            xt2[rr * 72 + cc] = ok ? xb[(gh << 8) + gw] : 0.f;
        } else {
            float2 v = ok ? *(const float2*)(xb + (((gh << 8) + gw) << 1)) : float2{0.f, 0.f};
            xt2[(rr * 72 + cc) * 2 + 0] = v.x;
            xt2[(rr * 72 + cc) * 2 + 1] = v.y;
        }
    }
    __syncthreads();
    // h1 tile compute: 396 pixels x 64ch; thread -> ch-octet (tid&7),
    // one pixel slot at a time (k=0..6); incremental rr/cc (no divides).
    {
        const int cg = tid & 7;
        const int ps = tid >> 3;
        float bias8[8];
        #pragma unroll
        for (int j = 0; j < 8; j++) bias8[j] = bt[cg * 8 + j];
        int p = ps, rr = 0, cc = ps;   // ps < 64 < 66
        #pragma unroll 1
        for (int k = 0; k < 7; k++) {
            if (p < 396) {
                int gh = h0 - 1 + rr, gw = w0 - 1 + cc;
                bool inb = (gh >= 0 && gh < 256 && gw >= 0 && gw < 256);
                int xbase = rr * 72 + cc;
                float acc[8];
                #pragma unroll
                for (int j = 0; j < 8; j++) acc[j] = bias8[j];
                #pragma unroll
                for (int tap = 0; tap < 9; tap++) {
                    const int dy = tap / 3, dx = tap % 3;
                    float4 wA = *(const float4*)&wtf[(tap * NCIN) * 64 + cg * 8];
                    float4 wB = *(const float4*)&wtf[(tap * NCIN) * 64 + cg * 8 + 4];
                    if (NCIN == 1) {
                        float xv = xt2[xbase + dy * 72 + dx];
                        acc[0] += xv * wA.x; acc[1] += xv * wA.y;
                        acc[2] += xv * wA.z; acc[3] += xv * wA.w;
                        acc[4] += xv * wB.x; acc[5] += xv * wB.y;
                        acc[6] += xv * wB.z; acc[7] += xv * wB.w;
                    } else {
                        float4 wC = *(const float4*)&wtf[(tap * 2 + 1) * 64 + cg * 8];
                        float4 wD = *(const float4*)&wtf[(tap * 2 + 1) * 64 + cg * 8 + 4];
                        float xv0 = xt2[(xbase + dy * 72 + dx) * 2 + 0];
                        float xv1 = xt2[(xbase + dy * 72 + dx) * 2 + 1];
                        acc[0] += xv0 * wA.x + xv1 * wC.x;
                        acc[1] += xv0 * wA.y + xv1 * wC.y;
                        acc[2] += xv0 * wA.z + xv1 * wC.z;
                        acc[3] += xv0 * wA.w + xv1 * wC.w;
                        acc[4] += xv0 * wB.x + xv1 * wD.x;
                        acc[5] += xv0 * wB.y + xv1 * wD.y;
                        acc[6] += xv0 * wB.z + xv1 * wD.z;
                        acc[7] += xv0 * wB.w + xv1 * wD.w;
                    }
                }
                short8 o;
                #pragma unroll
                for (int j = 0; j < 8; j++)
                    o[j] = inb ? (short)f2bf(fmaxf(acc[j], 0.f)) : (short)0;
                *(short8*)(tile + cg * TPS + p * 8) = o;
            }
            p += 64; cc += 64;
            if (cc >= 66) { cc -= 66; rr += 1; }
        }
    }
    __syncthreads();
    // MFMA K-loop: wave wid: row = wid&3, g-half = wid>>2
    int lane = tid & 63, wid = tid >> 6;
    int row = wid & 3, ghalf = wid >> 2;
    int nl = lane & 15, quad = lane >> 4;
    floatx4 acc[4][GH];
    floatx4 zero = {0.f, 0.f, 0.f, 0.f};
    #pragma unroll
    for (int mi = 0; mi < 4; mi++)
        #pragma unroll
        for (int g = 0; g < GH; g++) acc[mi][g] = zero;
    #pragma unroll
    for (int t = 0; t < 18; t++) {
        const int tap = t >> 1, hf = t & 1;
        const int dy = tap / 3, dx = tap % 3;
        const int cga = hf * 4 + quad;
        short8 A[4];
        #pragma unroll
        for (int mi = 0; mi < 4; mi++)
            A[mi] = *(const short8*)(tile + cga * TPS + ((row + dy) * 66 + mi * 16 + nl + dx) * 8);
        #pragma unroll
        for (int g = 0; g < GH; g++) {
            short8 B = *(const short8*)(bp + ((((ghalf * GH + g) * 18 + t) << 6) + lane) * 8);
            #pragma unroll
            for (int mi = 0; mi < 4; mi++)
                acc[mi][g] = __builtin_amdgcn_mfma_f32_16x16x32_bf16(A[mi], B, acc[mi][g], 0, 0, 0);
        }
    }
    size_t obase = ((size_t)((n * 256 + h0 + row)) << 8) + w0;
    #pragma unroll
    for (int g = 0; g < GH; g++) {
        int gg = ghalf * GH + g;
        float bb = bias2[gg * 16 + nl];
        #pragma unroll
        for (int mi = 0; mi < 4; mi++) {
            #pragma unroll
            for (int r = 0; r < 4; r++) {
                int pc = mi * 16 + quad * 4 + r;
                float v = fmaxf(acc[mi][g][r] + bb, 0.f);
                hout[(obase + pc) * (NG * 16) + gg * 16 + nl] = f2bf(v);
            }
        }
    }
}

// ---- conv3x3 64->81 + bias + softmax(81) + 9x9 adaptive filter (round-7) ----
__global__ __launch_bounds__(512, 4) void conv_softmax_apply(
    const unsigned short* __restrict__ h2b, const unsigned short* __restrict__ bp,
    const float* __restrict__ bias, const float* __restrict__ x,
    float* __restrict__ hout, int head) {
    __shared__ __align__(16) unsigned short tile[6 * 66 * 72];  // reused for logits 256*104
    __shared__ __align__(16) float xt[12 * 72];
    __shared__ float2 pp[512];
    int blk = blockIdx.x;
    int n = blk >> 8;
    int rem = blk & 255;
    int h0 = (rem >> 2) * 4;
    int w0 = (rem & 3) * 64;
    int tid = threadIdx.x;
    const unsigned short* hb = h2b + ((size_t)n << 22);
    for (int c = tid; c < 6 * 66 * 8; c += 512) {
        int ch8 = c & 7;
        int cc = (c >> 3) % 66;
        int rr = (c >> 3) / 66;
        int gh = h0 - 1 + rr, gw = w0 - 1 + cc;
        uint4 v = {0u, 0u, 0u, 0u};
        if (gh >= 0 && gh < 256 && gw >= 0 && gw < 256)
            v = *(const uint4*)(hb + (((gh << 8) + gw) << 6) + ch8 * 8);
        *(uint4*)(tile + (rr * 66 + cc) * 72 + ch8 * 8) = v;
    }
    const float* xb = x + ((size_t)n << 16);
    for (int c = tid; c < 12 * 72; c += 512) {
        int cc = c % 72, rr = c / 72;
        int gh = h0 - 4 + rr, gw = w0 - 4 + cc;
        xt[c] = (gh >= 0 && gh < 256 && gw >= 0 && gw < 256) ? xb[(gh << 8) + gw] : 0.f;
    }
    __syncthreads();
    int lane = tid & 63, wid = tid >> 6;
    int row = wid & 3, ghalf = wid >> 2;
    int nl = lane & 15, quad = lane >> 4;
    floatx4 acc[4][3];
    floatx4 zero = {0.f, 0.f, 0.f, 0.f};
    #pragma unroll
    for (int mi = 0; mi < 4; mi++)
        #pragma unroll
        for (int g = 0; g < 3; g++) acc[mi][g] = zero;
    #pragma unroll
    for (int t = 0; t < 18; t++) {
        const int tap = t >> 1, hf = t & 1;
        const int dy = tap / 3, dx = tap % 3;
        short8 A[4];
        #pragma unroll
        for (int mi = 0; mi < 4; mi++)
            A[mi] = *(const short8*)(tile + ((row + dy) * 66 + mi * 16 + nl + dx) * 72 + hf * 32 + quad * 8);
        #pragma unroll
        for (int g = 0; g < 3; g++) {
            short8 B = *(const short8*)(bp + ((((ghalf * 3 + g) * 18 + t) << 6) + lane) * 8);
            #pragma unroll
            for (int mi = 0; mi < 4; mi++)
                acc[mi][g] = __builtin_amdgcn_mfma_f32_16x16x32_bf16(A[mi], B, acc[mi][g], 0, 0, 0);
        }
    }
    __syncthreads();
    // logits (bias added) -> LDS [pixel][channel], bf16, stride 104
    #pragma unroll
    for (int g = 0; g < 3; g++) {
        int ch = (ghalf * 3 + g) * 16 + nl;
        float bb = (ch < 81) ? bias[ch] : 0.f;
        #pragma unroll
        for (int mi = 0; mi < 4; mi++) {
            #pragma unroll
            for (int r = 0; r < 4; r++) {
                int pl = row * 64 + mi * 16 + quad * 4 + r;
                tile[pl * 104 + ch] = f2bf(acc[mi][g][r] + bb);
            }
        }
    }
    __syncthreads();
    // epilogue: 2 threads per pixel; h=0 -> taps 0..40, h=1 -> taps 41..80
    int h = tid >> 8, pl = tid & 255;
    int r0 = pl >> 6, c0 = pl & 63;
    const unsigned short* lgp = tile + pl * 104;
    float sum = 0.f, dot = 0.f;
    if (h == 0) {
        short8 lg[6];
        #pragma unroll
        for (int jj = 0; jj < 6; jj++) lg[jj] = *(const short8*)(lgp + jj * 8);
        #pragma unroll
        for (int ch = 0; ch < 41; ch++) {
            float v = bf2f((unsigned short)lg[ch >> 3][ch & 7]);
            float e = __expf(v);
            sum += e;
            dot += e * xt[(r0 + ch / 9) * 72 + c0 + (ch % 9)];
        }
    } else {
        short8 lg[6];
        #pragma unroll
        for (int jj = 0; jj < 6; jj++) lg[jj] = *(const short8*)(lgp + (jj + 5) * 8);
        #pragma unroll
        for (int ch = 41; ch < 81; ch++) {
            float v = bf2f((unsigned short)lg[(ch >> 3) - 5][ch & 7]);
            float e = __expf(v);
            sum += e;
            dot += e * xt[(r0 + ch / 9) * 72 + c0 + (ch % 9)];
        }
    }
    pp[tid] = float2{sum, dot};
    __syncthreads();
    if (tid < 256) {
        float2 a = pp[tid], bq = pp[tid + 256];
        size_t gp = ((size_t)((n * 256 + h0 + r0)) << 8) + w0 + c0;
        hout[gp * 2 + head] = (a.y + bq.y) / (a.x + bq.x);
    }
}

// ---- conv3x3 64->1 + bias via MFMA tile (round-7) ---------------------------
__global__ __launch_bounds__(512, 4) void conv_64to1_mfma(
    const unsigned short* __restrict__ h2, const unsigned short* __restrict__ bp,
    const float* __restrict__ b, float* __restrict__ out) {
    __shared__ __align__(16) unsigned short tile[6 * 66 * 72];
    int blk = blockIdx.x;
    int n = blk >> 8;
    int rem = blk & 255;
    int h0 = (rem >> 2) * 4;
    int w0 = (rem & 3) * 64;
    int tid = threadIdx.x;
    const unsigned short* hb = h2 + ((size_t)n << 22);
    for (int c = tid; c < 6 * 66 * 8; c += 512) {
        int ch8 = c & 7;
        int cc = (c >> 3) % 66;
        int rr = (c >> 3) / 66;
        int gh = h0 - 1 + rr, gw = w0 - 1 + cc;
        uint4 v = {0u, 0u, 0u, 0u};
        if (gh >= 0 && gh < 256 && gw >= 0 && gw < 256)
            v = *(const uint4*)(hb + (((gh << 8) + gw) << 6) + ch8 * 8);
        *(uint4*)(tile + (rr * 66 + cc) * 72 + ch8 * 8) = v;
    }
    __syncthreads();
    int lane = tid & 63, wid = tid >> 6;
    int row = wid & 3, mh = wid >> 2;
    int nl = lane & 15, quad = lane >> 4;
    floatx4 acc[2];
    floatx4 zero = {0.f, 0.f, 0.f, 0.f};
    acc[0] = zero; acc[1] = zero;
    #pragma unroll
    for (int t = 0; t < 18; t++) {
        const int tap = t >> 1, hf = t & 1;
        const int dy = tap / 3, dx = tap % 3;
        short8 B = *(const short8*)(bp + ((t << 6) + lane) * 8);
        #pragma unroll
        for (int im = 0; im < 2; im++) {
            int mi = mh * 2 + im;
            short8 A = *(const short8*)(tile + ((row + dy) * 66 + mi * 16 + nl + dx) * 72 + hf * 32 + quad * 8);
            acc[im] = __builtin_amdgcn_mfma_f32_16x16x32_bf16(A, B, acc[im], 0, 0, 0);
        }
    }
    if (nl == 0) {
        float b0 = b[0];
        size_t obase = ((size_t)((n * 256 + h0 + row)) << 8) + w0;
        #pragma unroll
        for (int im = 0; im < 2; im++) {
            int mi = mh * 2 + im;
            #pragma unroll
            for (int r = 0; r < 4; r++)
                out[obase + mi * 16 + quad * 4 + r] = acc[im][r] + b0;
        }
    }
}

extern "C" void kernel_launch(void* const* d_in, const int* in_sizes, int n_in,
                              void* d_out, int out_size, void* d_ws, size_t ws_size,
                              hipStream_t stream) {
    const float* x     = (const float*)d_in[0];
    const float* g     = (const float*)d_in[1];
    const float* fx_w1 = (const float*)d_in[2];
    const float* fx_b1 = (const float*)d_in[3];
    const float* fx_w2 = (const float*)d_in[4];
    const float* fx_b2 = (const float*)d_in[5];
    const float* fx_w3 = (const float*)d_in[6];
    const float* fx_b3 = (const float*)d_in[7];
    const float* fg_w1 = (const float*)d_in[8];
    const float* fg_b1 = (const float*)d_in[9];
    const float* fg_w2 = (const float*)d_in[10];
    const float* fg_b2 = (const float*)d_in[11];
    const float* fg_w3 = (const float*)d_in[12];
    const float* fg_b3 = (const float*)d_in[13];
    const float* c1_w  = (const float*)d_in[14];
    const float* c1_b  = (const float*)d_in[15];
    const float* c2_w  = (const float*)d_in[16];
    const float* c2_b  = (const float*)d_in[17];
    const float* c3_w  = (const float*)d_in[18];
    const float* c3_b  = (const float*)d_in[19];
    float* out = (float*)d_out;

    // ---- workspace: h2 (per-chunk) + hin (persistent) + weight packs --------
    const size_t packElems = 230400;   // 6 packs, bf16 elements
    const size_t fixedB = (size_t)P_TOT * 2 * sizeof(float) + packElems * 2 + 256;
    int c = 16;
    while (c > 1 && fixedB + (size_t)c * P_IMG * 128 > ws_size) c >>= 1;
    size_t pcElems = (size_t)c * P_IMG * 64;

    unsigned short* h2 = (unsigned short*)d_ws;
    float* hin = (float*)(h2 + pcElems);
    unsigned short* bp0 = (unsigned short*)(hin + (size_t)P_TOT * 2);
    unsigned short* bp_w2x = bp0;
    unsigned short* bp_w3x = bp0 + 36864;
    unsigned short* bp_w2g = bp0 + 92160;
    unsigned short* bp_w3g = bp0 + 129024;
    unsigned short* bp_c2  = bp0 + 184320;
    unsigned short* bp_c3  = bp0 + 221184;

    dim3 blk(256);
    dim3 blk512(512);
    repack_all<<<900, blk, 0, stream>>>(fx_w2, fx_w3, fg_w2, fg_w3, c2_w, c3_w, bp0);

    const int nchunk = 16 / c;
    for (int ck = 0; ck < nchunk; ck++) {
        size_t po = (size_t)ck * c * P_IMG;
        conv_fused12<4, 1><<<c * 256, blk512, 0, stream>>>(x + po, fx_w1, fx_b1, bp_w2x, fx_b2, h2);
        conv_softmax_apply<<<c * 256, blk512, 0, stream>>>(h2, bp_w3x, fx_b3, x + po, hin + po * 2, 0);
    }
    for (int ck = 0; ck < nchunk; ck++) {
        size_t po = (size_t)ck * c * P_IMG;
        conv_fused12<4, 1><<<c * 256, blk512, 0, stream>>>(g + po, fg_w1, fg_b1, bp_w2g, fg_b2, h2);
        conv_softmax_apply<<<c * 256, blk512, 0, stream>>>(h2, bp_w3g, fg_b3, g + po, hin + po * 2, 1);
    }
    for (int ck = 0; ck < nchunk; ck++) {
        size_t po = (size_t)ck * c * P_IMG;
        conv_fused12<4, 2><<<c * 256, blk512, 0, stream>>>(hin + po * 2, c1_w, c1_b, bp_c2, c2_b, h2);
        conv_64to1_mfma<<<c * 256, blk512, 0, stream>>>(h2, bp_c3, c3_b, out + po);
    }
}

// Round 16
// 774.944 us; speedup vs baseline: 2.0682x; 2.0682x over previous
//
#include <hip/hip_runtime.h>
#include <stdint.h>

typedef __attribute__((ext_vector_type(8))) short short8;
typedef __attribute__((ext_vector_type(4))) float floatx4;

#define P_TOT (16 * 256 * 256)
#define P_IMG 65536
#define TPS 3208   // tile plane stride (shorts) per channel-octet: 400*8 + 8

__device__ __forceinline__ unsigned short f2bf(float f) {
    unsigned int u = __float_as_uint(f);
    return (unsigned short)((u + 0x7FFFu + ((u >> 16) & 1u)) >> 16);
}
__device__ __forceinline__ float bf2f(unsigned short h) {
    return __uint_as_float(((unsigned int)h) << 16);
}

// ---- single-launch repack: all 6 OIHW fp32 packs -> bf16 MFMA B-order -------
__global__ void repack_all(const float* __restrict__ w2x, const float* __restrict__ w3x,
                           const float* __restrict__ w2g, const float* __restrict__ w3g,
                           const float* __restrict__ c2w, const float* __restrict__ c3w,
                           unsigned short* __restrict__ bp) {
    int idx = blockIdx.x * 256 + threadIdx.x;
    if (idx >= 230400) return;
    const float* w; int creal, loc;
    if      (idx < 36864)  { w = w2x; creal = 64; loc = idx; }
    else if (idx < 92160)  { w = w3x; creal = 81; loc = idx - 36864; }
    else if (idx < 129024) { w = w2g; creal = 64; loc = idx - 92160; }
    else if (idx < 184320) { w = w3g; creal = 81; loc = idx - 129024; }
    else if (idx < 221184) { w = c2w; creal = 64; loc = idx - 184320; }
    else                   { w = c3w; creal = 1;  loc = idx - 221184; }
    int j = loc & 7;
    int lane = (loc >> 3) & 63;
    int gt = loc >> 9;            // g*18 + t
    int t = gt % 18;
    int n = (gt / 18) * 16 + (lane & 15);
    int tap = t >> 1, hf = t & 1;
    int dy = tap / 3, dx = tap % 3;
    int cin = hf * 32 + (lane >> 4) * 8 + j;
    float v = (n < creal) ? w[((n * 64 + cin) * 3 + dy) * 3 + dx] : 0.f;
    bp[idx] = f2bf(v);
}

// ---- fused conv3x3 (NCIN->64, relu) + conv3x3 (64->NG*16, relu) via MFMA ----
// h1 weights stay bf16 in LDS (hoisted as short8 = 36 regs, no spill; fp32
// hoisting spilled in r15 -> 892 MB scratch FETCH). Incremental rr/cc (no
// divides) + hoisted bias. (512,4) -> VGPR<=64, 2 blocks/CU (r14-proven).
template <int NG, int NCIN>
__global__ __launch_bounds__(512, 4) void conv_fused12(
    const float* __restrict__ xin, const float* __restrict__ w1,
    const float* __restrict__ b1, const unsigned short* __restrict__ bp,
    const float* __restrict__ bias2, unsigned short* __restrict__ hout) {
    constexpr int GH = NG / 2;
    __shared__ __align__(16) unsigned short tile[8 * TPS];      // [cg][pix<=400][8ch]
    __shared__ __align__(16) float xt2[8 * 72 * NCIN];
    __shared__ __align__(16) unsigned short wt[9 * 64 * NCIN];  // bf16
    __shared__ float bt[64];
    int blk = blockIdx.x;
    int n = blk >> 8;
    int rem = blk & 255;
    int h0 = (rem >> 2) * 4;
    int w0 = (rem & 3) * 64;
    int tid = threadIdx.x;
    // stage conv1 weights [tap*NCIN+ci][ch] (bf16) and bias
    for (int i = tid; i < 576 * NCIN; i += 512) {
        int ch = i & 63, tc = i >> 6;          // tc = tap*NCIN + ci
        int tap = tc / NCIN, ci = tc % NCIN;
        wt[tc * 64 + ch] = f2bf(w1[(ch * NCIN + ci) * 9 + tap]);
    }
    if (tid < 64) bt[tid] = b1[tid];
    // stage x tile: rows h0-2..h0+5, cols w0-2..w0+65 (zero-padded)
    const float* xb = xin + (((size_t)n) << 16) * NCIN;
    for (int i = tid; i < 8 * 68; i += 512) {
        int cc = i % 68, rr = i / 68;
        int gh = h0 - 2 + rr, gw = w0 - 2 + cc;
        bool ok = (gh >= 0 && gh < 256 && gw >= 0 && gw < 256);
        if (NCIN == 1) {
            xt2[rr * 72 + cc] = ok ? xb[(gh << 8) + gw] : 0.f;
        } else {
            float2 v = ok ? *(const float2*)(xb + (((gh << 8) + gw) << 1)) : float2{0.f, 0.f};
            xt2[(rr * 72 + cc) * 2 + 0] = v.x;
            xt2[(rr * 72 + cc) * 2 + 1] = v.y;
        }
    }
    __syncthreads();
    // h1 tile compute: 396 pixels x 64ch; thread -> ch-octet (tid&7),
    // one pixel slot at a time (k=0..6); incremental rr/cc (no divides).
    {
        const int cg = tid & 7;
        const int ps = tid >> 3;
        float bias8[8];
        #pragma unroll
        for (int j = 0; j < 8; j++) bias8[j] = bt[cg * 8 + j];
        int p = ps, rr = 0, cc = ps;   // ps < 64 < 66
        #pragma unroll 1
        for (int k = 0; k < 7; k++) {
            if (p < 396) {
                int gh = h0 - 1 + rr, gw = w0 - 1 + cc;
                bool inb = (gh >= 0 && gh < 256 && gw >= 0 && gw < 256);
                int xbase = rr * 72 + cc;
                float acc[8];
                #pragma unroll
                for (int j = 0; j < 8; j++) acc[j] = bias8[j];
                #pragma unroll
                for (int tap = 0; tap < 9; tap++) {
                    const int dy = tap / 3, dx = tap % 3;
                    short8 wv0 = *(const short8*)&wt[(tap * NCIN) * 64 + cg * 8];
                    if (NCIN == 1) {
                        float xv = xt2[xbase + dy * 72 + dx];
                        #pragma unroll
                        for (int j = 0; j < 8; j++)
                            acc[j] += xv * bf2f((unsigned short)wv0[j]);
                    } else {
                        short8 wv1 = *(const short8*)&wt[(tap * 2 + 1) * 64 + cg * 8];
                        float xv0 = xt2[(xbase + dy * 72 + dx) * 2 + 0];
                        float xv1 = xt2[(xbase + dy * 72 + dx) * 2 + 1];
                        #pragma unroll
                        for (int j = 0; j < 8; j++)
                            acc[j] += xv0 * bf2f((unsigned short)wv0[j])
                                    + xv1 * bf2f((unsigned short)wv1[j]);
                    }
                }
                short8 o;
                #pragma unroll
                for (int j = 0; j < 8; j++)
                    o[j] = inb ? (short)f2bf(fmaxf(acc[j], 0.f)) : (short)0;
                *(short8*)(tile + cg * TPS + p * 8) = o;
            }
            p += 64; cc += 64;
            if (cc >= 66) { cc -= 66; rr += 1; }
        }
    }
    __syncthreads();
    // MFMA K-loop: wave wid: row = wid&3, g-half = wid>>2
    int lane = tid & 63, wid = tid >> 6;
    int row = wid & 3, ghalf = wid >> 2;
    int nl = lane & 15, quad = lane >> 4;
    floatx4 acc[4][GH];
    floatx4 zero = {0.f, 0.f, 0.f, 0.f};
    #pragma unroll
    for (int mi = 0; mi < 4; mi++)
        #pragma unroll
        for (int g = 0; g < GH; g++) acc[mi][g] = zero;
    #pragma unroll
    for (int t = 0; t < 18; t++) {
        const int tap = t >> 1, hf = t & 1;
        const int dy = tap / 3, dx = tap % 3;
        const int cga = hf * 4 + quad;
        short8 A[4];
        #pragma unroll
        for (int mi = 0; mi < 4; mi++)
            A[mi] = *(const short8*)(tile + cga * TPS + ((row + dy) * 66 + mi * 16 + nl + dx) * 8);
        #pragma unroll
        for (int g = 0; g < GH; g++) {
            short8 B = *(const short8*)(bp + ((((ghalf * GH + g) * 18 + t) << 6) + lane) * 8);
            #pragma unroll
            for (int mi = 0; mi < 4; mi++)
                acc[mi][g] = __builtin_amdgcn_mfma_f32_16x16x32_bf16(A[mi], B, acc[mi][g], 0, 0, 0);
        }
    }
    size_t obase = ((size_t)((n * 256 + h0 + row)) << 8) + w0;
    #pragma unroll
    for (int g = 0; g < GH; g++) {
        int gg = ghalf * GH + g;
        float bb = bias2[gg * 16 + nl];
        #pragma unroll
        for (int mi = 0; mi < 4; mi++) {
            #pragma unroll
            for (int r = 0; r < 4; r++) {
                int pc = mi * 16 + quad * 4 + r;
                float v = fmaxf(acc[mi][g][r] + bb, 0.f);
                hout[(obase + pc) * (NG * 16) + gg * 16 + nl] = f2bf(v);
            }
        }
    }
}

// ---- conv3x3 64->81 + bias + softmax(81) + 9x9 adaptive filter (round-7) ----
__global__ __launch_bounds__(512, 4) void conv_softmax_apply(
    const unsigned short* __restrict__ h2b, const unsigned short* __restrict__ bp,
    const float* __restrict__ bias, const float* __restrict__ x,
    float* __restrict__ hout, int head) {
    __shared__ __align__(16) unsigned short tile[6 * 66 * 72];  // reused for logits 256*104
    __shared__ __align__(16) float xt[12 * 72];
    __shared__ float2 pp[512];
    int blk = blockIdx.x;
    int n = blk >> 8;
    int rem = blk & 255;
    int h0 = (rem >> 2) * 4;
    int w0 = (rem & 3) * 64;
    int tid = threadIdx.x;
    const unsigned short* hb = h2b + ((size_t)n << 22);
    for (int c = tid; c < 6 * 66 * 8; c += 512) {
        int ch8 = c & 7;
        int cc = (c >> 3) % 66;
        int rr = (c >> 3) / 66;
        int gh = h0 - 1 + rr, gw = w0 - 1 + cc;
        uint4 v = {0u, 0u, 0u, 0u};
        if (gh >= 0 && gh < 256 && gw >= 0 && gw < 256)
            v = *(const uint4*)(hb + (((gh << 8) + gw) << 6) + ch8 * 8);
        *(uint4*)(tile + (rr * 66 + cc) * 72 + ch8 * 8) = v;
    }
    const float* xb = x + ((size_t)n << 16);
    for (int c = tid; c < 12 * 72; c += 512) {
        int cc = c % 72, rr = c / 72;
        int gh = h0 - 4 + rr, gw = w0 - 4 + cc;
        xt[c] = (gh >= 0 && gh < 256 && gw >= 0 && gw < 256) ? xb[(gh << 8) + gw] : 0.f;
    }
    __syncthreads();
    int lane = tid & 63, wid = tid >> 6;
    int row = wid & 3, ghalf = wid >> 2;
    int nl = lane & 15, quad = lane >> 4;
    floatx4 acc[4][3];
    floatx4 zero = {0.f, 0.f, 0.f, 0.f};
    #pragma unroll
    for (int mi = 0; mi < 4; mi++)
        #pragma unroll
        for (int g = 0; g < 3; g++) acc[mi][g] = zero;
    #pragma unroll
    for (int t = 0; t < 18; t++) {
        const int tap = t >> 1, hf = t & 1;
        const int dy = tap / 3, dx = tap % 3;
        short8 A[4];
        #pragma unroll
        for (int mi = 0; mi < 4; mi++)
            A[mi] = *(const short8*)(tile + ((row + dy) * 66 + mi * 16 + nl + dx) * 72 + hf * 32 + quad * 8);
        #pragma unroll
        for (int g = 0; g < 3; g++) {
            short8 B = *(const short8*)(bp + ((((ghalf * 3 + g) * 18 + t) << 6) + lane) * 8);
            #pragma unroll
            for (int mi = 0; mi < 4; mi++)
                acc[mi][g] = __builtin_amdgcn_mfma_f32_16x16x32_bf16(A[mi], B, acc[mi][g], 0, 0, 0);
        }
    }
    __syncthreads();
    // logits (bias added) -> LDS [pixel][channel], bf16, stride 104
    #pragma unroll
    for (int g = 0; g < 3; g++) {
        int ch = (ghalf * 3 + g) * 16 + nl;
        float bb = (ch < 81) ? bias[ch] : 0.f;
        #pragma unroll
        for (int mi = 0; mi < 4; mi++) {
            #pragma unroll
            for (int r = 0; r < 4; r++) {
                int pl = row * 64 + mi * 16 + quad * 4 + r;
                tile[pl * 104 + ch] = f2bf(acc[mi][g][r] + bb);
            }
        }
    }
    __syncthreads();
    // epilogue: 2 threads per pixel; h=0 -> taps 0..40, h=1 -> taps 41..80
    int h = tid >> 8, pl = tid & 255;
    int r0 = pl >> 6, c0 = pl & 63;
    const unsigned short* lgp = tile + pl * 104;
    float sum = 0.f, dot = 0.f;
    if (h == 0) {
        short8 lg[6];
        #pragma unroll
        for (int jj = 0; jj < 6; jj++) lg[jj] = *(const short8*)(lgp + jj * 8);
        #pragma unroll
        for (int ch = 0; ch < 41; ch++) {
            float v = bf2f((unsigned short)lg[ch >> 3][ch & 7]);
            float e = __expf(v);
            sum += e;
            dot += e * xt[(r0 + ch / 9) * 72 + c0 + (ch % 9)];
        }
    } else {
        short8 lg[6];
        #pragma unroll
        for (int jj = 0; jj < 6; jj++) lg[jj] = *(const short8*)(lgp + (jj + 5) * 8);
        #pragma unroll
        for (int ch = 41; ch < 81; ch++) {
            float v = bf2f((unsigned short)lg[(ch >> 3) - 5][ch & 7]);
            float e = __expf(v);
            sum += e;
            dot += e * xt[(r0 + ch / 9) * 72 + c0 + (ch % 9)];
        }
    }
    pp[tid] = float2{sum, dot};
    __syncthreads();
    if (tid < 256) {
        float2 a = pp[tid], bq = pp[tid + 256];
        size_t gp = ((size_t)((n * 256 + h0 + r0)) << 8) + w0 + c0;
        hout[gp * 2 + head] = (a.y + bq.y) / (a.x + bq.x);
    }
}

// ---- conv3x3 64->1 + bias via MFMA tile (round-7) ---------------------------
__global__ __launch_bounds__(512, 4) void conv_64to1_mfma(
    const unsigned short* __restrict__ h2, const unsigned short* __restrict__ bp,
    const float* __restrict__ b, float* __restrict__ out) {
    __shared__ __align__(16) unsigned short tile[6 * 66 * 72];
    int blk = blockIdx.x;
    int n = blk >> 8;
    int rem = blk & 255;
    int h0 = (rem >> 2) * 4;
    int w0 = (rem & 3) * 64;
    int tid = threadIdx.x;
    const unsigned short* hb = h2 + ((size_t)n << 22);
    for (int c = tid; c < 6 * 66 * 8; c += 512) {
        int ch8 = c & 7;
        int cc = (c >> 3) % 66;
        int rr = (c >> 3) / 66;
        int gh = h0 - 1 + rr, gw = w0 - 1 + cc;
        uint4 v = {0u, 0u, 0u, 0u};
        if (gh >= 0 && gh < 256 && gw >= 0 && gw < 256)
            v = *(const uint4*)(hb + (((gh << 8) + gw) << 6) + ch8 * 8);
        *(uint4*)(tile + (rr * 66 + cc) * 72 + ch8 * 8) = v;
    }
    __syncthreads();
    int lane = tid & 63, wid = tid >> 6;
    int row = wid & 3, mh = wid >> 2;
    int nl = lane & 15, quad = lane >> 4;
    floatx4 acc[2];
    floatx4 zero = {0.f, 0.f, 0.f, 0.f};
    acc[0] = zero; acc[1] = zero;
    #pragma unroll
    for (int t = 0; t < 18; t++) {
        const int tap = t >> 1, hf = t & 1;
        const int dy = tap / 3, dx = tap % 3;
        short8 B = *(const short8*)(bp + ((t << 6) + lane) * 8);
        #pragma unroll
        for (int im = 0; im < 2; im++) {
            int mi = mh * 2 + im;
            short8 A = *(const short8*)(tile + ((row + dy) * 66 + mi * 16 + nl + dx) * 72 + hf * 32 + quad * 8);
            acc[im] = __builtin_amdgcn_mfma_f32_16x16x32_bf16(A, B, acc[im], 0, 0, 0);
        }
    }
    if (nl == 0) {
        float b0 = b[0];
        size_t obase = ((size_t)((n * 256 + h0 + row)) << 8) + w0;
        #pragma unroll
        for (int im = 0; im < 2; im++) {
            int mi = mh * 2 + im;
            #pragma unroll
            for (int r = 0; r < 4; r++)
                out[obase + mi * 16 + quad * 4 + r] = acc[im][r] + b0;
        }
    }
}

extern "C" void kernel_launch(void* const* d_in, const int* in_sizes, int n_in,
                              void* d_out, int out_size, void* d_ws, size_t ws_size,
                              hipStream_t stream) {
    const float* x     = (const float*)d_in[0];
    const float* g     = (const float*)d_in[1];
    const float* fx_w1 = (const float*)d_in[2];
    const float* fx_b1 = (const float*)d_in[3];
    const float* fx_w2 = (const float*)d_in[4];
    const float* fx_b2 = (const float*)d_in[5];
    const float* fx_w3 = (const float*)d_in[6];
    const float* fx_b3 = (const float*)d_in[7];
    const float* fg_w1 = (const float*)d_in[8];
    const float* fg_b1 = (const float*)d_in[9];
    const float* fg_w2 = (const float*)d_in[10];
    const float* fg_b2 = (const float*)d_in[11];
    const float* fg_w3 = (const float*)d_in[12];
    const float* fg_b3 = (const float*)d_in[13];
    const float* c1_w  = (const float*)d_in[14];
    const float* c1_b  = (const float*)d_in[15];
    const float* c2_w  = (const float*)d_in[16];
    const float* c2_b  = (const float*)d_in[17];
    const float* c3_w  = (const float*)d_in[18];
    const float* c3_b  = (const float*)d_in[19];
    float* out = (float*)d_out;

    // ---- workspace: h2 (per-chunk) + hin (persistent) + weight packs --------
    const size_t packElems = 230400;   // 6 packs, bf16 elements
    const size_t fixedB = (size_t)P_TOT * 2 * sizeof(float) + packElems * 2 + 256;
    int c = 16;
    while (c > 1 && fixedB + (size_t)c * P_IMG * 128 > ws_size) c >>= 1;
    size_t pcElems = (size_t)c * P_IMG * 64;

    unsigned short* h2 = (unsigned short*)d_ws;
    float* hin = (float*)(h2 + pcElems);
    unsigned short* bp0 = (unsigned short*)(hin + (size_t)P_TOT * 2);
    unsigned short* bp_w2x = bp0;
    unsigned short* bp_w3x = bp0 + 36864;
    unsigned short* bp_w2g = bp0 + 92160;
    unsigned short* bp_w3g = bp0 + 129024;
    unsigned short* bp_c2  = bp0 + 184320;
    unsigned short* bp_c3  = bp0 + 221184;

    dim3 blk(256);
    dim3 blk512(512);
    repack_all<<<900, blk, 0, stream>>>(fx_w2, fx_w3, fg_w2, fg_w3, c2_w, c3_w, bp0);

    const int nchunk = 16 / c;
    for (int ck = 0; ck < nchunk; ck++) {
        size_t po = (size_t)ck * c * P_IMG;
        conv_fused12<4, 1><<<c * 256, blk512, 0, stream>>>(x + po, fx_w1, fx_b1, bp_w2x, fx_b2, h2);
        conv_softmax_apply<<<c * 256, blk512, 0, stream>>>(h2, bp_w3x, fx_b3, x + po, hin + po * 2, 0);
    }
    for (int ck = 0; ck < nchunk; ck++) {
        size_t po = (size_t)ck * c * P_IMG;
        conv_fused12<4, 1><<<c * 256, blk512, 0, stream>>>(g + po, fg_w1, fg_b1, bp_w2g, fg_b2, h2);
        conv_softmax_apply<<<c * 256, blk512, 0, stream>>>(h2, bp_w3g, fg_b3, g + po, hin + po * 2, 1);
    }
    for (int ck = 0; ck < nchunk; ck++) {
        size_t po = (size_t)ck * c * P_IMG;
        conv_fused12<4, 2><<<c * 256, blk512, 0, stream>>>(hin + po * 2, c1_w, c1_b, bp_c2, c2_b, h2);
        conv_64to1_mfma<<<c * 256, blk512, 0, stream>>>(h2, bp_c3, c3_b, out + po);
    }
}

// Round 17
// 694.624 us; speedup vs baseline: 2.3073x; 1.1156x over previous
//
#include <hip/hip_runtime.h>
#include <stdint.h>

typedef __attribute__((ext_vector_type(8))) short short8;
typedef __attribute__((ext_vector_type(4))) float floatx4;

#define P_TOT (16 * 256 * 256)
#define P_IMG 65536
#define TPS 3208   // tile plane stride (shorts) per channel-octet: 400*8 + 8

__device__ __forceinline__ unsigned short f2bf(float f) {
    unsigned int u = __float_as_uint(f);
    return (unsigned short)((u + 0x7FFFu + ((u >> 16) & 1u)) >> 16);
}
__device__ __forceinline__ float bf2f(unsigned short h) {
    return __uint_as_float(((unsigned int)h) << 16);
}

// ---- single-launch repack: all 6 OIHW fp32 packs -> bf16 MFMA B-order -------
__global__ void repack_all(const float* __restrict__ w2x, const float* __restrict__ w3x,
                           const float* __restrict__ w2g, const float* __restrict__ w3g,
                           const float* __restrict__ c2w, const float* __restrict__ c3w,
                           unsigned short* __restrict__ bp) {
    int idx = blockIdx.x * 256 + threadIdx.x;
    if (idx >= 230400) return;
    const float* w; int creal, loc;
    if      (idx < 36864)  { w = w2x; creal = 64; loc = idx; }
    else if (idx < 92160)  { w = w3x; creal = 81; loc = idx - 36864; }
    else if (idx < 129024) { w = w2g; creal = 64; loc = idx - 92160; }
    else if (idx < 184320) { w = w3g; creal = 81; loc = idx - 129024; }
    else if (idx < 221184) { w = c2w; creal = 64; loc = idx - 184320; }
    else                   { w = c3w; creal = 1;  loc = idx - 221184; }
    int j = loc & 7;
    int lane = (loc >> 3) & 63;
    int gt = loc >> 9;            // g*18 + t
    int t = gt % 18;
    int n = (gt / 18) * 16 + (lane & 15);
    int tap = t >> 1, hf = t & 1;
    int dy = tap / 3, dx = tap % 3;
    int cin = hf * 32 + (lane >> 4) * 8 + j;
    float v = (n < creal) ? w[((n * 64 + cin) * 3 + dy) * 3 + dx] : 0.f;
    bp[idx] = f2bf(v);
}

// ---- fused conv3x3 (NCIN->64, relu) + conv3x3 (64->NG*16, relu) via MFMA ----
// h1 phase ALSO via MFMA: M=396 px, N=64 ch, K=9*NCIN padded to 32 -> one
// 16x16x32 step per (m-tile, ch-group). B zero-padded for k>=K so A may carry
// garbage in padded columns. Layout conventions identical to the main K-loop.
template <int NG, int NCIN>
__global__ __launch_bounds__(512, 4) void conv_fused12(
    const float* __restrict__ xin, const float* __restrict__ w1,
    const float* __restrict__ b1, const unsigned short* __restrict__ bp,
    const float* __restrict__ bias2, unsigned short* __restrict__ hout) {
    constexpr int GH = NG / 2;
    __shared__ __align__(16) unsigned short tile[8 * TPS];      // [cg][pix<=400][8ch]
    __shared__ __align__(16) unsigned short xtb[576 * NCIN];    // bf16, [ci][8][72]
    __shared__ __align__(16) unsigned short wt[9 * 64 * NCIN];  // bf16 conv1 w
    __shared__ float bt[64];
    __shared__ int kofs[32];
    int blk = blockIdx.x;
    int n = blk >> 8;
    int rem = blk & 255;
    int h0 = (rem >> 2) * 4;
    int w0 = (rem & 3) * 64;
    int tid = threadIdx.x;
    // stage conv1 weights [tap*NCIN+ci][ch] (bf16) and bias
    for (int i = tid; i < 576 * NCIN; i += 512) {
        int ch = i & 63, tc = i >> 6;          // tc = tap*NCIN + ci
        int tap = tc / NCIN, ci = tc % NCIN;
        wt[tc * 64 + ch] = f2bf(w1[(ch * NCIN + ci) * 9 + tap]);
    }
    if (tid < 64) bt[tid] = b1[tid];
    // k -> xtb offset table (k = ci*9 + tap; invalid k -> 0, B is zero there)
    if (tid < 32) {
        int k = tid, off = 0;
        if (k < 9 * NCIN) {
            int ci = k / 9, tap = k - ci * 9;
            off = ci * 576 + (tap / 3) * 72 + (tap % 3);
        }
        kofs[tid] = off;
    }
    // stage x tile (bf16): rows h0-2..h0+5, cols w0-2..w0+65 (zero-padded)
    const float* xb = xin + (((size_t)n) << 16) * NCIN;
    for (int i = tid; i < 8 * 68; i += 512) {
        int cc = i % 68, rr = i / 68;
        int gh = h0 - 2 + rr, gw = w0 - 2 + cc;
        bool ok = (gh >= 0 && gh < 256 && gw >= 0 && gw < 256);
        if (NCIN == 1) {
            xtb[rr * 72 + cc] = ok ? f2bf(xb[(gh << 8) + gw]) : 0;
        } else {
            float2 v = ok ? *(const float2*)(xb + (((gh << 8) + gw) << 1)) : float2{0.f, 0.f};
            xtb[rr * 72 + cc] = f2bf(v.x);
            xtb[576 + rr * 72 + cc] = f2bf(v.y);
        }
    }
    __syncthreads();
    int lane = tid & 63, wid = tid >> 6;
    int nl = lane & 15, quad = lane >> 4;
    // ---- h1 via MFMA: wave wid handles m-tiles {wid, wid+8, wid+16, ...<25} --
    {
        int kof[8];
        #pragma unroll
        for (int j = 0; j < 8; j++) kof[j] = kofs[quad * 8 + j];
        // decode k once per j
        int kci[8], ktap[8]; bool kval[8];
        #pragma unroll
        for (int j = 0; j < 8; j++) {
            int k = quad * 8 + j;
            kval[j] = (k < 9 * NCIN);
            int ci = k / 9;
            kci[j] = ci; ktap[j] = k - ci * 9;
        }
        short8 Bf[4];
        #pragma unroll
        for (int g = 0; g < 4; g++) {
            #pragma unroll
            for (int j = 0; j < 8; j++) {
                unsigned short v = 0;
                if (kval[j]) v = wt[(ktap[j] * NCIN + kci[j]) * 64 + g * 16 + nl];
                Bf[g][j] = (short)v;
            }
        }
        float bias4[4];
        #pragma unroll
        for (int g = 0; g < 4; g++) bias4[g] = bt[g * 16 + nl];
        floatx4 zf = {0.f, 0.f, 0.f, 0.f};
        #pragma unroll 1
        for (int mt = wid; mt < 25; mt += 8) {
            int p0 = mt * 16 + nl;
            int rr0 = p0 / 66, cc0 = p0 - rr0 * 66;
            int xbase = rr0 * 72 + cc0;
            short8 A;
            #pragma unroll
            for (int j = 0; j < 8; j++) A[j] = (short)xtb[xbase + kof[j]];
            floatx4 cfr[4];
            #pragma unroll
            for (int g = 0; g < 4; g++)
                cfr[g] = __builtin_amdgcn_mfma_f32_16x16x32_bf16(A, Bf[g], zf, 0, 0, 0);
            int pb = mt * 16 + quad * 4;
            #pragma unroll
            for (int r = 0; r < 4; r++) {
                int p = pb + r;
                int rrp = p / 66, ccp = p - rrp * 66;
                int gh = h0 - 1 + rrp, gw = w0 - 1 + ccp;
                bool inb = (gh >= 0 && gh < 256 && gw >= 0 && gw < 256);
                #pragma unroll
                for (int g = 0; g < 4; g++) {
                    int ch = g * 16 + nl;
                    float v = fmaxf(cfr[g][r] + bias4[g], 0.f);
                    tile[(ch >> 3) * TPS + p * 8 + (ch & 7)] = inb ? f2bf(v) : (unsigned short)0;
                }
            }
        }
    }
    __syncthreads();
    // ---- main MFMA K-loop: wave wid: row = wid&3, g-half = wid>>2 -----------
    int row = wid & 3, ghalf = wid >> 2;
    floatx4 acc[4][GH];
    floatx4 zero = {0.f, 0.f, 0.f, 0.f};
    #pragma unroll
    for (int mi = 0; mi < 4; mi++)
        #pragma unroll
        for (int g = 0; g < GH; g++) acc[mi][g] = zero;
    #pragma unroll
    for (int t = 0; t < 18; t++) {
        const int tap = t >> 1, hf = t & 1;
        const int dy = tap / 3, dx = tap % 3;
        const int cga = hf * 4 + quad;
        short8 A[4];
        #pragma unroll
        for (int mi = 0; mi < 4; mi++)
            A[mi] = *(const short8*)(tile + cga * TPS + ((row + dy) * 66 + mi * 16 + nl + dx) * 8);
        #pragma unroll
        for (int g = 0; g < GH; g++) {
            short8 B = *(const short8*)(bp + ((((ghalf * GH + g) * 18 + t) << 6) + lane) * 8);
            #pragma unroll
            for (int mi = 0; mi < 4; mi++)
                acc[mi][g] = __builtin_amdgcn_mfma_f32_16x16x32_bf16(A[mi], B, acc[mi][g], 0, 0, 0);
        }
    }
    size_t obase = ((size_t)((n * 256 + h0 + row)) << 8) + w0;
    #pragma unroll
    for (int g = 0; g < GH; g++) {
        int gg = ghalf * GH + g;
        float bb = bias2[gg * 16 + nl];
        #pragma unroll
        for (int mi = 0; mi < 4; mi++) {
            #pragma unroll
            for (int r = 0; r < 4; r++) {
                int pc = mi * 16 + quad * 4 + r;
                float v = fmaxf(acc[mi][g][r] + bb, 0.f);
                hout[(obase + pc) * (NG * 16) + gg * 16 + nl] = f2bf(v);
            }
        }
    }
}

// ---- conv3x3 64->81 + bias + softmax(81) + 9x9 adaptive filter (round-7) ----
__global__ __launch_bounds__(512, 4) void conv_softmax_apply(
    const unsigned short* __restrict__ h2b, const unsigned short* __restrict__ bp,
    const float* __restrict__ bias, const float* __restrict__ x,
    float* __restrict__ hout, int head) {
    __shared__ __align__(16) unsigned short tile[6 * 66 * 72];  // reused for logits 256*104
    __shared__ __align__(16) float xt[12 * 72];
    __shared__ float2 pp[512];
    int blk = blockIdx.x;
    int n = blk >> 8;
    int rem = blk & 255;
    int h0 = (rem >> 2) * 4;
    int w0 = (rem & 3) * 64;
    int tid = threadIdx.x;
    const unsigned short* hb = h2b + ((size_t)n << 22);
    for (int c = tid; c < 6 * 66 * 8; c += 512) {
        int ch8 = c & 7;
        int cc = (c >> 3) % 66;
        int rr = (c >> 3) / 66;
        int gh = h0 - 1 + rr, gw = w0 - 1 + cc;
        uint4 v = {0u, 0u, 0u, 0u};
        if (gh >= 0 && gh < 256 && gw >= 0 && gw < 256)
            v = *(const uint4*)(hb + (((gh << 8) + gw) << 6) + ch8 * 8);
        *(uint4*)(tile + (rr * 66 + cc) * 72 + ch8 * 8) = v;
    }
    const float* xb = x + ((size_t)n << 16);
    for (int c = tid; c < 12 * 72; c += 512) {
        int cc = c % 72, rr = c / 72;
        int gh = h0 - 4 + rr, gw = w0 - 4 + cc;
        xt[c] = (gh >= 0 && gh < 256 && gw >= 0 && gw < 256) ? xb[(gh << 8) + gw] : 0.f;
    }
    __syncthreads();
    int lane = tid & 63, wid = tid >> 6;
    int row = wid & 3, ghalf = wid >> 2;
    int nl = lane & 15, quad = lane >> 4;
    floatx4 acc[4][3];
    floatx4 zero = {0.f, 0.f, 0.f, 0.f};
    #pragma unroll
    for (int mi = 0; mi < 4; mi++)
        #pragma unroll
        for (int g = 0; g < 3; g++) acc[mi][g] = zero;
    #pragma unroll
    for (int t = 0; t < 18; t++) {
        const int tap = t >> 1, hf = t & 1;
        const int dy = tap / 3, dx = tap % 3;
        short8 A[4];
        #pragma unroll
        for (int mi = 0; mi < 4; mi++)
            A[mi] = *(const short8*)(tile + ((row + dy) * 66 + mi * 16 + nl + dx) * 72 + hf * 32 + quad * 8);
        #pragma unroll
        for (int g = 0; g < 3; g++) {
            short8 B = *(const short8*)(bp + ((((ghalf * 3 + g) * 18 + t) << 6) + lane) * 8);
            #pragma unroll
            for (int mi = 0; mi < 4; mi++)
                acc[mi][g] = __builtin_amdgcn_mfma_f32_16x16x32_bf16(A[mi], B, acc[mi][g], 0, 0, 0);
        }
    }
    __syncthreads();
    // logits (bias added) -> LDS [pixel][channel], bf16, stride 104
    #pragma unroll
    for (int g = 0; g < 3; g++) {
        int ch = (ghalf * 3 + g) * 16 + nl;
        float bb = (ch < 81) ? bias[ch] : 0.f;
        #pragma unroll
        for (int mi = 0; mi < 4; mi++) {
            #pragma unroll
            for (int r = 0; r < 4; r++) {
                int pl = row * 64 + mi * 16 + quad * 4 + r;
                tile[pl * 104 + ch] = f2bf(acc[mi][g][r] + bb);
            }
        }
    }
    __syncthreads();
    // epilogue: 2 threads per pixel; h=0 -> taps 0..40, h=1 -> taps 41..80
    int h = tid >> 8, pl = tid & 255;
    int r0 = pl >> 6, c0 = pl & 63;
    const unsigned short* lgp = tile + pl * 104;
    float sum = 0.f, dot = 0.f;
    if (h == 0) {
        short8 lg[6];
        #pragma unroll
        for (int jj = 0; jj < 6; jj++) lg[jj] = *(const short8*)(lgp + jj * 8);
        #pragma unroll
        for (int ch = 0; ch < 41; ch++) {
            float v = bf2f((unsigned short)lg[ch >> 3][ch & 7]);
            float e = __expf(v);
            sum += e;
            dot += e * xt[(r0 + ch / 9) * 72 + c0 + (ch % 9)];
        }
    } else {
        short8 lg[6];
        #pragma unroll
        for (int jj = 0; jj < 6; jj++) lg[jj] = *(const short8*)(lgp + (jj + 5) * 8);
        #pragma unroll
        for (int ch = 41; ch < 81; ch++) {
            float v = bf2f((unsigned short)lg[(ch >> 3) - 5][ch & 7]);
            float e = __expf(v);
            sum += e;
            dot += e * xt[(r0 + ch / 9) * 72 + c0 + (ch % 9)];
        }
    }
    pp[tid] = float2{sum, dot};
    __syncthreads();
    if (tid < 256) {
        float2 a = pp[tid], bq = pp[tid + 256];
        size_t gp = ((size_t)((n * 256 + h0 + r0)) << 8) + w0 + c0;
        hout[gp * 2 + head] = (a.y + bq.y) / (a.x + bq.x);
    }
}

// ---- conv3x3 64->1 + bias via MFMA tile (round-7) ---------------------------
__global__ __launch_bounds__(512, 4) void conv_64to1_mfma(
    const unsigned short* __restrict__ h2, const unsigned short* __restrict__ bp,
    const float* __restrict__ b, float* __restrict__ out) {
    __shared__ __align__(16) unsigned short tile[6 * 66 * 72];
    int blk = blockIdx.x;
    int n = blk >> 8;
    int rem = blk & 255;
    int h0 = (rem >> 2) * 4;
    int w0 = (rem & 3) * 64;
    int tid = threadIdx.x;
    const unsigned short* hb = h2 + ((size_t)n << 22);
    for (int c = tid; c < 6 * 66 * 8; c += 512) {
        int ch8 = c & 7;
        int cc = (c >> 3) % 66;
        int rr = (c >> 3) / 66;
        int gh = h0 - 1 + rr, gw = w0 - 1 + cc;
        uint4 v = {0u, 0u, 0u, 0u};
        if (gh >= 0 && gh < 256 && gw >= 0 && gw < 256)
            v = *(const uint4*)(hb + (((gh << 8) + gw) << 6) + ch8 * 8);
        *(uint4*)(tile + (rr * 66 + cc) * 72 + ch8 * 8) = v;
    }
    __syncthreads();
    int lane = tid & 63, wid = tid >> 6;
    int row = wid & 3, mh = wid >> 2;
    int nl = lane & 15, quad = lane >> 4;
    floatx4 acc[2];
    floatx4 zero = {0.f, 0.f, 0.f, 0.f};
    acc[0] = zero; acc[1] = zero;
    #pragma unroll
    for (int t = 0; t < 18; t++) {
        const int tap = t >> 1, hf = t & 1;
        const int dy = tap / 3, dx = tap % 3;
        short8 B = *(const short8*)(bp + ((t << 6) + lane) * 8);
        #pragma unroll
        for (int im = 0; im < 2; im++) {
            int mi = mh * 2 + im;
            short8 A = *(const short8*)(tile + ((row + dy) * 66 + mi * 16 + nl + dx) * 72 + hf * 32 + quad * 8);
            acc[im] = __builtin_amdgcn_mfma_f32_16x16x32_bf16(A, B, acc[im], 0, 0, 0);
        }
    }
    if (nl == 0) {
        float b0 = b[0];
        size_t obase = ((size_t)((n * 256 + h0 + row)) << 8) + w0;
        #pragma unroll
        for (int im = 0; im < 2; im++) {
            int mi = mh * 2 + im;
            #pragma unroll
            for (int r = 0; r < 4; r++)
                out[obase + mi * 16 + quad * 4 + r] = acc[im][r] + b0;
        }
    }
}

extern "C" void kernel_launch(void* const* d_in, const int* in_sizes, int n_in,
                              void* d_out, int out_size, void* d_ws, size_t ws_size,
                              hipStream_t stream) {
    const float* x     = (const float*)d_in[0];
    const float* g     = (const float*)d_in[1];
    const float* fx_w1 = (const float*)d_in[2];
    const float* fx_b1 = (const float*)d_in[3];
    const float* fx_w2 = (const float*)d_in[4];
    const float* fx_b2 = (const float*)d_in[5];
    const float* fx_w3 = (const float*)d_in[6];
    const float* fx_b3 = (const float*)d_in[7];
    const float* fg_w1 = (const float*)d_in[8];
    const float* fg_b1 = (const float*)d_in[9];
    const float* fg_w2 = (const float*)d_in[10];
    const float* fg_b2 = (const float*)d_in[11];
    const float* fg_w3 = (const float*)d_in[12];
    const float* fg_b3 = (const float*)d_in[13];
    const float* c1_w  = (const float*)d_in[14];
    const float* c1_b  = (const float*)d_in[15];
    const float* c2_w  = (const float*)d_in[16];
    const float* c2_b  = (const float*)d_in[17];
    const float* c3_w  = (const float*)d_in[18];
    const float* c3_b  = (const float*)d_in[19];
    float* out = (float*)d_out;

    // ---- workspace: h2 (per-chunk) + hin (persistent) + weight packs --------
    const size_t packElems = 230400;   // 6 packs, bf16 elements
    const size_t fixedB = (size_t)P_TOT * 2 * sizeof(float) + packElems * 2 + 256;
    int c = 16;
    while (c > 1 && fixedB + (size_t)c * P_IMG * 128 > ws_size) c >>= 1;
    size_t pcElems = (size_t)c * P_IMG * 64;

    unsigned short* h2 = (unsigned short*)d_ws;
    float* hin = (float*)(h2 + pcElems);
    unsigned short* bp0 = (unsigned short*)(hin + (size_t)P_TOT * 2);
    unsigned short* bp_w2x = bp0;
    unsigned short* bp_w3x = bp0 + 36864;
    unsigned short* bp_w2g = bp0 + 92160;
    unsigned short* bp_w3g = bp0 + 129024;
    unsigned short* bp_c2  = bp0 + 184320;
    unsigned short* bp_c3  = bp0 + 221184;

    dim3 blk(256);
    dim3 blk512(512);
    repack_all<<<900, blk, 0, stream>>>(fx_w2, fx_w3, fg_w2, fg_w3, c2_w, c3_w, bp0);

    const int nchunk = 16 / c;
    for (int ck = 0; ck < nchunk; ck++) {
        size_t po = (size_t)ck * c * P_IMG;
        conv_fused12<4, 1><<<c * 256, blk512, 0, stream>>>(x + po, fx_w1, fx_b1, bp_w2x, fx_b2, h2);
        conv_softmax_apply<<<c * 256, blk512, 0, stream>>>(h2, bp_w3x, fx_b3, x + po, hin + po * 2, 0);
    }
    for (int ck = 0; ck < nchunk; ck++) {
        size_t po = (size_t)ck * c * P_IMG;
        conv_fused12<4, 1><<<c * 256, blk512, 0, stream>>>(g + po, fg_w1, fg_b1, bp_w2g, fg_b2, h2);
        conv_softmax_apply<<<c * 256, blk512, 0, stream>>>(h2, bp_w3g, fg_b3, g + po, hin + po * 2, 1);
    }
    for (int ck = 0; ck < nchunk; ck++) {
        size_t po = (size_t)ck * c * P_IMG;
        conv_fused12<4, 2><<<c * 256, blk512, 0, stream>>>(hin + po * 2, c1_w, c1_b, bp_c2, c2_b, h2);
        conv_64to1_mfma<<<c * 256, blk512, 0, stream>>>(h2, bp_c3, c3_b, out + po);
    }
}